// Round 4
// baseline (5093.992 us; speedup 1.0000x reference)
//
#include <hip/hip_runtime.h>
#include <math.h>

#define NN 50000
#define NE 200000
#define NH 4
#define NG 100
#define EPSBN 1e-5f
#define SLOPE 0.2f

typedef __attribute__((ext_vector_type(8))) short bf16x8;
typedef __attribute__((ext_vector_type(4))) float f32x4;

__device__ __forceinline__ unsigned short f2bf(float f) {
    unsigned u = __float_as_uint(f);
    unsigned r = (u + 0x7fffu + ((u >> 16) & 1u)) >> 16;   // RNE
    return (unsigned short)r;
}
__device__ __forceinline__ float bf2f(unsigned short s) {
    return __uint_as_float(((unsigned)s) << 16);
}

__global__ void fill_val(float* p, int n, float v) {
    int i = blockIdx.x * 256 + threadIdx.x;
    if (i < n) p[i] = v;
}

// ---------- weight prep: Wh/Wl[n][k] = split-bf16 of W[k][n] ----------
template<bool LO>
__global__ void wsplit(const float* __restrict__ W, unsigned short* __restrict__ Wh,
                       unsigned short* __restrict__ Wl, int K, int N) {
    int idx = blockIdx.x * 256 + threadIdx.x;
    if (idx >= K * N) return;
    int k = idx / N, n = idx % N;
    float w = W[idx];
    unsigned short h = f2bf(w);
    Wh[(size_t)n * K + k] = h;
    if (LO) Wl[(size_t)n * K + k] = f2bf(w - bf2f(h));
}

// ---------- split-bf16 MFMA GEMM ----------
// C[M,N] (= A@B + bias | += A@B) with A f32 [M,K] (hi/lo split on the fly),
// B pre-split bf16 [N,ldbt] (transposed). acc += Ah*Bh + Al*Bh (+ Ah*Bl if BLO).
// BM=BN=128, BK=64, 256 thr = 4 waves (2x2), 4x4 frags of mfma_f32_16x16x32_bf16.
// A frag: row=lane&15, k=(lane>>4)*8+j. C/D: col=lane&15, row=(lane>>4)*4+reg.
template<bool BLO>
__launch_bounds__(256, 2)
__global__ void gemm_split(const float* __restrict__ A,
                           const unsigned short* __restrict__ Bh,
                           const unsigned short* __restrict__ Bl,
                           const float* __restrict__ bias, float* __restrict__ C,
                           int M, int N, int K, int ldbt, int accum) {
    __shared__ unsigned short Ah[128 * 64];
    __shared__ unsigned short Al[128 * 64];
    __shared__ unsigned short Bhs[128 * 64];
    __shared__ unsigned short Bls[BLO ? 128 * 64 : 16];
    char* AhB = (char*)Ah; char* AlB = (char*)Al;
    char* BhB = (char*)Bhs; char* BlB = (char*)Bls;
    const int tid = threadIdx.x;
    const int m0 = blockIdx.x * 128, n0 = blockIdx.y * 128;
    const int lane = tid & 63, wid = tid >> 6;
    const int wr = wid >> 1, wc = wid & 1;
    const int srow = tid >> 1, shalf = tid & 1;   // staging row, 32-elem k-half
    const int sbyte = shalf * 64;
    const int swz = (srow & 7) << 4;
    const bool ok = (m0 + srow) < M;

    f32x4 acc[4][4];
#pragma unroll
    for (int m = 0; m < 4; ++m)
#pragma unroll
        for (int n = 0; n < 4; ++n) acc[m][n] = (f32x4){0.f, 0.f, 0.f, 0.f};

    for (int k0 = 0; k0 < K; k0 += 64) {
        // ---- stage A (f32 -> hi/lo bf16), 32 elems per thread ----
        const float* Ap = A + (size_t)(m0 + srow) * K + k0 + shalf * 32;
#pragma unroll
        for (int i = 0; i < 4; ++i) {
            float vv[8];
            if (ok) {
                *(float4*)&vv[0] = *(const float4*)(Ap + i * 8);
                *(float4*)&vv[4] = *(const float4*)(Ap + i * 8 + 4);
            } else {
#pragma unroll
                for (int j = 0; j < 8; ++j) vv[j] = 0.f;
            }
            uint4 uh, ul;
            unsigned* uhp = &uh.x; unsigned* ulp = &ul.x;
#pragma unroll
            for (int j = 0; j < 4; ++j) {
                float a0 = vv[2 * j], a1 = vv[2 * j + 1];
                unsigned short h0 = f2bf(a0), h1 = f2bf(a1);
                unsigned short l0 = f2bf(a0 - bf2f(h0)), l1 = f2bf(a1 - bf2f(h1));
                uhp[j] = (unsigned)h0 | ((unsigned)h1 << 16);
                ulp[j] = (unsigned)l0 | ((unsigned)l1 << 16);
            }
            *(uint4*)(AhB + srow * 128 + ((sbyte + i * 16) ^ swz)) = uh;
            *(uint4*)(AlB + srow * 128 + ((sbyte + i * 16) ^ swz)) = ul;
        }
        // ---- stage B hi (and lo): 32 bf16 = 64 B = 4 x uint4 (i*8 shorts!) ----
        {
            const unsigned short* Bp = Bh + (size_t)(n0 + srow) * ldbt + k0 + shalf * 32;
#pragma unroll
            for (int i = 0; i < 4; ++i)
                *(uint4*)(BhB + srow * 128 + ((sbyte + i * 16) ^ swz)) =
                    *(const uint4*)(Bp + i * 8);
        }
        if (BLO) {
            const unsigned short* Bq = Bl + (size_t)(n0 + srow) * ldbt + k0 + shalf * 32;
#pragma unroll
            for (int i = 0; i < 4; ++i)
                *(uint4*)(BlB + srow * 128 + ((sbyte + i * 16) ^ swz)) =
                    *(const uint4*)(Bq + i * 8);
        }
        __syncthreads();
#pragma unroll
        for (int kk = 0; kk < 2; ++kk) {
            const int kb = kk * 64 + (lane >> 4) * 16;
            bf16x8 ah[4], al[4], bh[4], bl[4];
#pragma unroll
            for (int m = 0; m < 4; ++m) {
                int row = wr * 64 + m * 16 + (lane & 15);
                int off = row * 128 + (kb ^ ((row & 7) << 4));
                ah[m] = *(const bf16x8*)(AhB + off);
                al[m] = *(const bf16x8*)(AlB + off);
            }
#pragma unroll
            for (int n = 0; n < 4; ++n) {
                int row = wc * 64 + n * 16 + (lane & 15);
                int off = row * 128 + (kb ^ ((row & 7) << 4));
                bh[n] = *(const bf16x8*)(BhB + off);
                if (BLO) bl[n] = *(const bf16x8*)(BlB + off);
            }
#pragma unroll
            for (int m = 0; m < 4; ++m)
#pragma unroll
                for (int n = 0; n < 4; ++n) {
                    acc[m][n] = __builtin_amdgcn_mfma_f32_16x16x32_bf16(
                        ah[m], bh[n], acc[m][n], 0, 0, 0);
                    acc[m][n] = __builtin_amdgcn_mfma_f32_16x16x32_bf16(
                        al[m], bh[n], acc[m][n], 0, 0, 0);
                    if (BLO)
                        acc[m][n] = __builtin_amdgcn_mfma_f32_16x16x32_bf16(
                            ah[m], bl[n], acc[m][n], 0, 0, 0);
                }
        }
        __syncthreads();
    }
    // ---- epilogue (f32 out) ----
#pragma unroll
    for (int n = 0; n < 4; ++n) {
        int gcol = n0 + wc * 64 + n * 16 + (lane & 15);
        float bv = accum ? 0.f : bias[gcol];
#pragma unroll
        for (int m = 0; m < 4; ++m) {
#pragma unroll
            for (int r = 0; r < 4; ++r) {
                int grow = m0 + wr * 64 + m * 16 + (lane >> 4) * 4 + r;
                if (grow < M) {
                    size_t o = (size_t)grow * N + gcol;
                    C[o] = accum ? (C[o] + acc[m][n][r]) : (acc[m][n][r] + bv);
                }
            }
        }
    }
}

// ---------- edge pass 1: logit -> ex (stored) + den atomicAdd ----------
// 64 lanes per edge, 16 edges per 1024-thr block; f32 gathers.
template<int NHEADS, bool EXBF16>
__launch_bounds__(1024)
__global__ void edge_score(const float* __restrict__ xl, const float* __restrict__ xr,
                           const int* __restrict__ ei, const float* __restrict__ ea,
                           const float* __restrict__ We, int ldwe,
                           const float* __restrict__ att,
                           void* __restrict__ exq, float* __restrict__ den) {
    __shared__ float sWe[12 * 256];
    __shared__ float sAtt[256];
    for (int t = threadIdx.x; t < 12 * 256; t += 1024) {
        int r = t >> 8, c = t & 255;
        sWe[t] = We[(size_t)r * ldwe + c];
    }
    if (threadIdx.x < 256) sAtt[threadIdx.x] = att[threadIdx.x];
    __syncthreads();
    const int e = blockIdx.x * 16 + (threadIdx.x >> 6);
    const int lane = threadIdx.x & 63;
    const int src = ei[e], dst = ei[NE + e];
    float eav[12];
#pragma unroll
    for (int d = 0; d < 12; ++d) eav[d] = ea[(size_t)e * 12 + d];
    const int cf = lane * 4;
    float4 xl4 = *(const float4*)(xl + (size_t)src * 256 + cf);
    float4 xr4 = *(const float4*)(xr + (size_t)dst * 256 + cf);
    const float* lp = &xl4.x; const float* rp = &xr4.x;
    float part = 0.f;
#pragma unroll
    for (int j = 0; j < 4; ++j) {
        int c = cf + j;
        float ecf = 0.f;
#pragma unroll
        for (int d = 0; d < 12; ++d) ecf = fmaf(eav[d], sWe[d * 256 + c], ecf);
        float mv = lp[j] + rp[j] + ecf;
        mv = mv > 0.f ? mv : SLOPE * mv;
        part = fmaf(mv, sAtt[c], part);
    }
    constexpr int RED = 64 / NHEADS;   // 64 (1 head) | 16 (4 heads)
#pragma unroll
    for (int off = RED / 2; off > 0; off >>= 1) part += __shfl_xor(part, off);
    if ((lane & (RED - 1)) == 0) {
        int h = (NHEADS == 4) ? (lane >> 4) : 0;
        float exv = __expf(part);   // no max-sub: |logit| small, alpha invariant
        if (EXBF16) {
            unsigned short eb = f2bf(exv);
            ((unsigned short*)exq)[(size_t)e * NHEADS + h] = eb;
            exv = bf2f(eb);         // keep num/den consistent
        } else {
            ((float*)exq)[(size_t)e * NHEADS + h] = exv;
        }
        unsafeAtomicAdd(&den[(size_t)dst * NHEADS + h], exv);
    }
}

// ---------- edge pass 2: agg[dst] += xl[src] * ex/den[dst] ----------
template<int NHEADS, bool EXBF16>
__launch_bounds__(256)
__global__ void edge_agg(const float* __restrict__ xl, const int* __restrict__ ei,
                         const void* __restrict__ exq, const float* __restrict__ den,
                         float* __restrict__ agg) {
    const int e = blockIdx.x * 4 + (threadIdx.x >> 6);
    const int lane = threadIdx.x & 63;
    const int src = ei[e], dst = ei[NE + e];
    const int cf = lane * 4;
    const int h = (NHEADS == 4) ? (lane >> 4) : 0;
    float exv = EXBF16 ? bf2f(((const unsigned short*)exq)[(size_t)e * NHEADS + h])
                       : ((const float*)exq)[(size_t)e * NHEADS + h];
    float alpha = exv / (den[(size_t)dst * NHEADS + h] + 1e-16f);
    float4 v = *(const float4*)(xl + (size_t)src * 256 + cf);
    const float* vp = &v.x;
    float* ag = agg + (size_t)dst * 256 + cf;
#pragma unroll
    for (int j = 0; j < 4; ++j)
        unsafeAtomicAdd(&ag[j], vp[j] * alpha);
}

// ---------- out = bn(relu(in + bias)) over [NN,256] ----------
__global__ void bias_relu_bn(const float* __restrict__ in, const float* __restrict__ b,
                             const float* __restrict__ gam, const float* __restrict__ bet,
                             const float* __restrict__ mu, const float* __restrict__ var,
                             float* __restrict__ outp) {
    int i4 = blockIdx.x * 256 + threadIdx.x;   // grid exact: NN*64
    int c4 = (i4 & 63) << 2;
    float4 x = *(const float4*)&in[(size_t)i4 * 4];
    const float* xp = &x.x;
    float o[4];
#pragma unroll
    for (int j = 0; j < 4; ++j) {
        int c = c4 + j;
        float t = fmaxf(xp[j] + b[c], 0.f);
        o[j] = (t - mu[c]) * rsqrtf(var[c] + EPSBN) * gam[c] + bet[c];
    }
    *(float4*)&outp[(size_t)i4 * 4] = make_float4(o[0], o[1], o[2], o[3]);
}

// ---------- head MLP ----------
__launch_bounds__(64)
__global__ void head_mlp(const float* __restrict__ h2, const int* __restrict__ n_nodes,
                         const float* __restrict__ Wf1, const float* __restrict__ bf1,
                         const float* __restrict__ Wf2, const float* __restrict__ bf2,
                         float* __restrict__ out) {
    const int g = blockIdx.x;
    const int t = threadIdx.x;
    int acc = 0;
    for (int i = t; i <= g; i += 64) acc += n_nodes[i];
#pragma unroll
    for (int off = 32; off > 0; off >>= 1) acc += __shfl_xor(acc, off);
    const int node = acc - 1;
    __shared__ float row[256];
    for (int i = t; i < 256; i += 64) row[i] = h2[(size_t)node * 256 + i];
    __syncthreads();
    float hid = bf1[t];
    for (int k = 0; k < 256; ++k) hid = fmaf(row[k], Wf1[k * 64 + t], hid);
    hid = fmaxf(hid, 0.f);
    float p = hid * Wf2[t];
#pragma unroll
    for (int off = 32; off > 0; off >>= 1) p += __shfl_xor(p, off);
    if (t == 0) out[g] = p + bf2[0];
}

// ================= host-side sequence, templated on ws budget =================
template<bool FULL>
static void run_all(void* const* d_in, float* out, char* ws, hipStream_t stream) {
    const float* x   = (const float*)d_in[0];
    const int*   ei  = (const int*)d_in[1];
    const float* ea  = (const float*)d_in[2];
    const int*   nnd = (const int*)d_in[3];
    const float* Wl1 = (const float*)d_in[4];
    const float* bl1 = (const float*)d_in[5];
    const float* Wr1 = (const float*)d_in[6];
    const float* br1 = (const float*)d_in[7];
    const float* We1 = (const float*)d_in[8];
    const float* att1= (const float*)d_in[9];
    const float* b1  = (const float*)d_in[10];
    const float* g1  = (const float*)d_in[11];
    const float* be1 = (const float*)d_in[12];
    const float* m1  = (const float*)d_in[13];
    const float* v1  = (const float*)d_in[14];
    const float* Wl2 = (const float*)d_in[15];
    const float* bl2 = (const float*)d_in[16];
    const float* Wr2 = (const float*)d_in[17];
    const float* br2 = (const float*)d_in[18];
    const float* We2 = (const float*)d_in[19];
    const float* att2= (const float*)d_in[20];
    const float* b2  = (const float*)d_in[21];
    const float* g2  = (const float*)d_in[22];
    const float* be2 = (const float*)d_in[23];
    const float* m2  = (const float*)d_in[24];
    const float* v2  = (const float*)d_in[25];
    const float* Wf1 = (const float*)d_in[26];
    const float* bf1 = (const float*)d_in[27];
    const float* Wf2 = (const float*)d_in[28];
    const float* bf2 = (const float*)d_in[29];

    const size_t PB = (size_t)NN * 256 * 4;          // 51.2 MB panel
    const size_t WB = (size_t)262144 * 2;            // 0.5 MB per bf16 weight copy
    size_t off = 0;
    float* bufA = (float*)(ws + off); off += PB;     // xl_h -> h1_h
    float* bufB = (float*)(ws + off); off += PB;     // xr_h -> agg
    float* xl2  = (float*)(ws + off); off += PB;
    float* xr2  = (float*)(ws + off); off += PB;
    void*  ex   = (void*)(ws + off); off += (size_t)NE * NH * (FULL ? 4 : 2);
    float* den  = (float*)(ws + off); off += (size_t)NN * NH * 4;
    unsigned short* Wl1h = (unsigned short*)(ws + off); off += WB;
    unsigned short* Wr1h = (unsigned short*)(ws + off); off += WB;
    unsigned short* Wl2h = (unsigned short*)(ws + off); off += WB;
    unsigned short* Wr2h = (unsigned short*)(ws + off); off += WB;
    unsigned short *Wl1l = nullptr, *Wr1l = nullptr, *Wl2l = nullptr, *Wr2l = nullptr;
    if (FULL) {
        Wl1l = (unsigned short*)(ws + off); off += WB;
        Wr1l = (unsigned short*)(ws + off); off += WB;
        Wl2l = (unsigned short*)(ws + off); off += WB;
        Wr2l = (unsigned short*)(ws + off); off += WB;
    }

    // weight prep
    wsplit<FULL><<<1024, 256, 0, stream>>>(Wl1, Wl1h, Wl1l, 256, 1024);
    wsplit<FULL><<<1024, 256, 0, stream>>>(Wr1, Wr1h, Wr1l, 256, 1024);
    wsplit<FULL><<<1024, 256, 0, stream>>>(Wl2, Wl2h, Wl2l, 1024, 256);
    wsplit<FULL><<<1024, 256, 0, stream>>>(Wr2, Wr2h, Wr2l, 1024, 256);

    const dim3 gg((NN + 127) / 128, 2);

    for (int h = 0; h < NH; ++h) {
        gemm_split<FULL><<<gg, 256, 0, stream>>>(
            x, Wl1h + (size_t)h * 65536, FULL ? Wl1l + (size_t)h * 65536 : nullptr,
            bl1 + h * 256, bufA, NN, 256, 256, 256, 0);
        gemm_split<FULL><<<gg, 256, 0, stream>>>(
            x, Wr1h + (size_t)h * 65536, FULL ? Wr1l + (size_t)h * 65536 : nullptr,
            br1 + h * 256, bufB, NN, 256, 256, 256, 0);
        hipMemsetAsync(den, 0, (size_t)NN * 4, stream);
        edge_score<1, false><<<NE / 16, 1024, 0, stream>>>(
            bufA, bufB, ei, ea, We1 + h * 256, 1024, att1 + h * 256, ex, den);
        hipMemsetAsync(bufB, 0, PB, stream);          // xr dead -> agg
        edge_agg<1, false><<<NE / 4, 256, 0, stream>>>(bufA, ei, ex, den, bufB);
        bias_relu_bn<<<NN * 64 / 256, 256, 0, stream>>>(
            bufB, b1 + h * 256, g1 + h * 256, be1 + h * 256,
            m1 + h * 256, v1 + h * 256, bufA);        // h1_h -> bufA
        // layer-2 partial-K accumulation (ldbt = 1024, K-chunk offset h*256)
        gemm_split<FULL><<<gg, 256, 0, stream>>>(
            bufA, Wl2h + h * 256, FULL ? Wl2l + h * 256 : nullptr,
            bl2, xl2, NN, 256, 256, 1024, h > 0 ? 1 : 0);
        gemm_split<FULL><<<gg, 256, 0, stream>>>(
            bufA, Wr2h + h * 256, FULL ? Wr2l + h * 256 : nullptr,
            br2, xr2, NN, 256, 256, 1024, h > 0 ? 1 : 0);
    }

    // layer 2 (4 heads at once)
    hipMemsetAsync(den, 0, (size_t)NN * NH * 4, stream);
    edge_score<4, !FULL><<<NE / 16, 1024, 0, stream>>>(
        xl2, xr2, ei, ea, We2, 256, att2, ex, den);
    hipMemsetAsync(bufB, 0, PB, stream);
    edge_agg<4, !FULL><<<NE / 4, 256, 0, stream>>>(xl2, ei, ex, den, bufB);
    bias_relu_bn<<<NN * 64 / 256, 256, 0, stream>>>(
        bufB, b2, g2, be2, m2, v2, bufA);
    head_mlp<<<NG, 64, 0, stream>>>(bufA, nnd, Wf1, bf1, Wf2, bf2, out);
}

extern "C" void kernel_launch(void* const* d_in, const int* in_sizes, int n_in,
                              void* d_out, int out_size, void* d_ws, size_t ws_size,
                              hipStream_t stream) {
    float* out = (float*)d_out;
    const size_t PB = (size_t)NN * 256 * 4;
    const size_t base = 4 * PB + (size_t)NN * NH * 4;
    const size_t need_full = base + (size_t)NE * NH * 4 + 8 * (size_t)262144 * 2;
    const size_t need_trim = base + (size_t)NE * NH * 2 + 4 * (size_t)262144 * 2;
    if (ws_size >= need_full) {
        run_all<true>(d_in, out, (char*)d_ws, stream);
    } else if (ws_size >= need_trim) {
        run_all<false>(d_in, out, (char*)d_ws, stream);
    } else {
        fill_val<<<(out_size + 255) / 256, 256, 0, stream>>>(out, out_size, 1e30f);
    }
}

// Round 5
// 1949.795 us; speedup vs baseline: 2.6126x; 2.6126x over previous
//
#include <hip/hip_runtime.h>
#include <math.h>

#define NN 50000
#define NE 200000
#define NH 4
#define NG 100
#define EPSBN 1e-5f
#define SLOPE 0.2f

typedef __attribute__((ext_vector_type(8))) short bf16x8;
typedef __attribute__((ext_vector_type(4))) float f32x4;

__device__ __forceinline__ unsigned short f2bf(float f) {
    unsigned u = __float_as_uint(f);
    unsigned r = (u + 0x7fffu + ((u >> 16) & 1u)) >> 16;   // RNE
    return (unsigned short)r;
}
__device__ __forceinline__ float bf2f(unsigned short s) {
    return __uint_as_float(((unsigned)s) << 16);
}

__global__ void fill_val(float* p, int n, float v) {
    int i = blockIdx.x * 256 + threadIdx.x;
    if (i < n) p[i] = v;
}

// ---------- weight prep: Wh/Wl[n][k] = split-bf16 of W[k][n] ----------
__global__ void wsplit(const float* __restrict__ W, unsigned short* __restrict__ Wh,
                       unsigned short* __restrict__ Wl, int K, int N) {
    int idx = blockIdx.x * 256 + threadIdx.x;
    if (idx >= K * N) return;
    int k = idx / N, n = idx % N;
    float w = W[idx];
    unsigned short h = f2bf(w);
    Wh[(size_t)n * K + k] = h;
    Wl[(size_t)n * K + k] = f2bf(w - bf2f(h));
}

// ---------- split-bf16 MFMA GEMM (verbatim from round 4, BLO=true path) ----------
__launch_bounds__(256, 2)
__global__ void gemm_split(const float* __restrict__ A,
                           const unsigned short* __restrict__ Bh,
                           const unsigned short* __restrict__ Bl,
                           const float* __restrict__ bias, float* __restrict__ C,
                           int M, int N, int K, int ldbt, int accum) {
    __shared__ unsigned short Ah[128 * 64];
    __shared__ unsigned short Al[128 * 64];
    __shared__ unsigned short Bhs[128 * 64];
    __shared__ unsigned short Bls[128 * 64];
    char* AhB = (char*)Ah; char* AlB = (char*)Al;
    char* BhB = (char*)Bhs; char* BlB = (char*)Bls;
    const int tid = threadIdx.x;
    const int m0 = blockIdx.x * 128, n0 = blockIdx.y * 128;
    const int lane = tid & 63, wid = tid >> 6;
    const int wr = wid >> 1, wc = wid & 1;
    const int srow = tid >> 1, shalf = tid & 1;
    const int sbyte = shalf * 64;
    const int swz = (srow & 7) << 4;
    const bool ok = (m0 + srow) < M;

    f32x4 acc[4][4];
#pragma unroll
    for (int m = 0; m < 4; ++m)
#pragma unroll
        for (int n = 0; n < 4; ++n) acc[m][n] = (f32x4){0.f, 0.f, 0.f, 0.f};

    for (int k0 = 0; k0 < K; k0 += 64) {
        const float* Ap = A + (size_t)(m0 + srow) * K + k0 + shalf * 32;
#pragma unroll
        for (int i = 0; i < 4; ++i) {
            float vv[8];
            if (ok) {
                *(float4*)&vv[0] = *(const float4*)(Ap + i * 8);
                *(float4*)&vv[4] = *(const float4*)(Ap + i * 8 + 4);
            } else {
#pragma unroll
                for (int j = 0; j < 8; ++j) vv[j] = 0.f;
            }
            uint4 uh, ul;
            unsigned* uhp = &uh.x; unsigned* ulp = &ul.x;
#pragma unroll
            for (int j = 0; j < 4; ++j) {
                float a0 = vv[2 * j], a1 = vv[2 * j + 1];
                unsigned short h0 = f2bf(a0), h1 = f2bf(a1);
                unsigned short l0 = f2bf(a0 - bf2f(h0)), l1 = f2bf(a1 - bf2f(h1));
                uhp[j] = (unsigned)h0 | ((unsigned)h1 << 16);
                ulp[j] = (unsigned)l0 | ((unsigned)l1 << 16);
            }
            *(uint4*)(AhB + srow * 128 + ((sbyte + i * 16) ^ swz)) = uh;
            *(uint4*)(AlB + srow * 128 + ((sbyte + i * 16) ^ swz)) = ul;
        }
        {
            const unsigned short* Bp = Bh + (size_t)(n0 + srow) * ldbt + k0 + shalf * 32;
#pragma unroll
            for (int i = 0; i < 4; ++i)
                *(uint4*)(BhB + srow * 128 + ((sbyte + i * 16) ^ swz)) =
                    *(const uint4*)(Bp + i * 8);
        }
        {
            const unsigned short* Bq = Bl + (size_t)(n0 + srow) * ldbt + k0 + shalf * 32;
#pragma unroll
            for (int i = 0; i < 4; ++i)
                *(uint4*)(BlB + srow * 128 + ((sbyte + i * 16) ^ swz)) =
                    *(const uint4*)(Bq + i * 8);
        }
        __syncthreads();
#pragma unroll
        for (int kk = 0; kk < 2; ++kk) {
            const int kb = kk * 64 + (lane >> 4) * 16;
            bf16x8 ah[4], al[4], bh[4], bl[4];
#pragma unroll
            for (int m = 0; m < 4; ++m) {
                int row = wr * 64 + m * 16 + (lane & 15);
                int off = row * 128 + (kb ^ ((row & 7) << 4));
                ah[m] = *(const bf16x8*)(AhB + off);
                al[m] = *(const bf16x8*)(AlB + off);
            }
#pragma unroll
            for (int n = 0; n < 4; ++n) {
                int row = wc * 64 + n * 16 + (lane & 15);
                int off = row * 128 + (kb ^ ((row & 7) << 4));
                bh[n] = *(const bf16x8*)(BhB + off);
                bl[n] = *(const bf16x8*)(BlB + off);
            }
#pragma unroll
            for (int m = 0; m < 4; ++m)
#pragma unroll
                for (int n = 0; n < 4; ++n) {
                    acc[m][n] = __builtin_amdgcn_mfma_f32_16x16x32_bf16(
                        ah[m], bh[n], acc[m][n], 0, 0, 0);
                    acc[m][n] = __builtin_amdgcn_mfma_f32_16x16x32_bf16(
                        al[m], bh[n], acc[m][n], 0, 0, 0);
                    acc[m][n] = __builtin_amdgcn_mfma_f32_16x16x32_bf16(
                        ah[m], bl[n], acc[m][n], 0, 0, 0);
                }
        }
        __syncthreads();
    }
#pragma unroll
    for (int n = 0; n < 4; ++n) {
        int gcol = n0 + wc * 64 + n * 16 + (lane & 15);
        float bv = accum ? 0.f : bias[gcol];
#pragma unroll
        for (int m = 0; m < 4; ++m) {
#pragma unroll
            for (int r = 0; r < 4; ++r) {
                int grow = m0 + wr * 64 + m * 16 + (lane >> 4) * 4 + r;
                if (grow < M) {
                    size_t o = (size_t)grow * N + gcol;
                    C[o] = accum ? (C[o] + acc[m][n][r]) : (acc[m][n][r] + bv);
                }
            }
        }
    }
}

// ---------- CSR build over dst ----------
__global__ void csr_count(const int* __restrict__ ei, int* __restrict__ cnt) {
    int e = blockIdx.x * 256 + threadIdx.x;
    if (e < NE) atomicAdd(&cnt[ei[NE + e]], 1);
}

// one block, 1024 threads, each owns 49 consecutive rows (1024*49 = 50176 >= NN)
__launch_bounds__(1024)
__global__ void csr_offsets(const int* __restrict__ cnt, int* __restrict__ off,
                            int* __restrict__ cursor) {
    __shared__ int s[1024];
    const int t = threadIdx.x;
    const int PER = 49;
    const int base = t * PER;
    int sum = 0;
    for (int i = 0; i < PER; ++i) {
        int idx = base + i;
        if (idx < NN) sum += cnt[idx];
    }
    s[t] = sum;
    __syncthreads();
    for (int d = 1; d < 1024; d <<= 1) {
        int v = (t >= d) ? s[t - d] : 0;
        __syncthreads();
        s[t] += v;
        __syncthreads();
    }
    int run = s[t] - sum;   // exclusive prefix of this thread's chunk
    for (int i = 0; i < PER; ++i) {
        int idx = base + i;
        if (idx < NN) {
            off[idx] = run;
            cursor[idx] = run;
            run += cnt[idx];
            if (idx == NN - 1) off[NN] = run;
        }
    }
}

__global__ void csr_fill(const int* __restrict__ ei, int* __restrict__ cursor,
                         int* __restrict__ eidl) {
    int e = blockIdx.x * 256 + threadIdx.x;
    if (e < NE) {
        int d = ei[NE + e];
        int p = atomicAdd(&cursor[d], 1);
        eidl[p] = e;
    }
}

// ---------- fused node-centric pass: logits+softmax+aggregate+bias+relu+bn ----------
// 1024 threads = 16 waves = 16 nodes/block; grid = NN/16 = 3125 (exact).
// outp may alias xr_in: each xr row is read only by its owner wave before write.
template<int NHEADS>
__launch_bounds__(1024)
__global__ void node_fused(const float* __restrict__ xl, const float* xr_in,
                           const int* __restrict__ off, const int* __restrict__ eidl,
                           const int* __restrict__ ei, const float* __restrict__ ea,
                           const float* __restrict__ We, int ldwe,
                           const float* __restrict__ att,
                           const float* __restrict__ bias, const float* __restrict__ gam,
                           const float* __restrict__ bet, const float* __restrict__ mu,
                           const float* __restrict__ var, float* outp) {
    __shared__ float sWe[12 * 256];
    __shared__ float sAtt[256];
    for (int t = threadIdx.x; t < 12 * 256; t += 1024)
        sWe[t] = We[(size_t)(t >> 8) * ldwe + (t & 255)];
    if (threadIdx.x < 256) sAtt[threadIdx.x] = att[threadIdx.x];
    __syncthreads();

    const int n = blockIdx.x * 16 + (threadIdx.x >> 6);
    const int lane = threadIdx.x & 63;
    const int cf = lane * 4;
    float4 xr4 = *(const float4*)(xr_in + (size_t)n * 256 + cf);
    const float* rp = &xr4.x;
    float acc[4] = {0.f, 0.f, 0.f, 0.f};
    float den = 0.f;
    const int beg = off[n], end = off[n + 1];
    for (int k = beg; k < end; ++k) {
        const int e = eidl[k];
        const int src = ei[e];
        float eav[12];
        const float2* eap = (const float2*)(ea + (size_t)e * 12);
#pragma unroll
        for (int d = 0; d < 6; ++d) {
            float2 w = eap[d];
            eav[2 * d] = w.x; eav[2 * d + 1] = w.y;
        }
        float4 xl4 = *(const float4*)(xl + (size_t)src * 256 + cf);
        const float* lp = &xl4.x;
        float part = 0.f;
#pragma unroll
        for (int j = 0; j < 4; ++j) {
            int c = cf + j;
            float ecf = 0.f;
#pragma unroll
            for (int d = 0; d < 12; ++d) ecf = fmaf(eav[d], sWe[d * 256 + c], ecf);
            float mv = lp[j] + rp[j] + ecf;
            mv = mv > 0.f ? mv : SLOPE * mv;
            part = fmaf(mv, sAtt[c], part);
        }
        constexpr int RED = 64 / NHEADS;   // 64 (1 head) | 16 (4 heads)
#pragma unroll
        for (int o = RED / 2; o > 0; o >>= 1) part += __shfl_xor(part, o);
        float ex = __expf(part);   // no max-sub: |logit| small; alpha invariant
        den += ex;
#pragma unroll
        for (int j = 0; j < 4; ++j) acc[j] = fmaf(ex, lp[j], acc[j]);
    }
    const float inv = 1.f / (den + 1e-16f);
    float o[4];
#pragma unroll
    for (int j = 0; j < 4; ++j) {
        int c = cf + j;
        float t = fmaxf(acc[j] * inv + bias[c], 0.f);
        o[j] = (t - mu[c]) * rsqrtf(var[c] + EPSBN) * gam[c] + bet[c];
    }
    *(float4*)(outp + (size_t)n * 256 + cf) = make_float4(o[0], o[1], o[2], o[3]);
}

// ---------- head MLP ----------
__launch_bounds__(64)
__global__ void head_mlp(const float* __restrict__ h2, const int* __restrict__ n_nodes,
                         const float* __restrict__ Wf1, const float* __restrict__ bf1,
                         const float* __restrict__ Wf2, const float* __restrict__ bf2,
                         float* __restrict__ out) {
    const int g = blockIdx.x;
    const int t = threadIdx.x;
    int acc = 0;
    for (int i = t; i <= g; i += 64) acc += n_nodes[i];
#pragma unroll
    for (int off = 32; off > 0; off >>= 1) acc += __shfl_xor(acc, off);
    const int node = acc - 1;
    __shared__ float row[256];
    for (int i = t; i < 256; i += 64) row[i] = h2[(size_t)node * 256 + i];
    __syncthreads();
    float hid = bf1[t];
    for (int k = 0; k < 256; ++k) hid = fmaf(row[k], Wf1[k * 64 + t], hid);
    hid = fmaxf(hid, 0.f);
    float p = hid * Wf2[t];
#pragma unroll
    for (int off = 32; off > 0; off >>= 1) p += __shfl_xor(p, off);
    if (t == 0) out[g] = p + bf2[0];
}

extern "C" void kernel_launch(void* const* d_in, const int* in_sizes, int n_in,
                              void* d_out, int out_size, void* d_ws, size_t ws_size,
                              hipStream_t stream) {
    const float* x   = (const float*)d_in[0];
    const int*   ei  = (const int*)d_in[1];
    const float* ea  = (const float*)d_in[2];
    const int*   nnd = (const int*)d_in[3];
    const float* Wl1 = (const float*)d_in[4];
    const float* bl1 = (const float*)d_in[5];
    const float* Wr1 = (const float*)d_in[6];
    const float* br1 = (const float*)d_in[7];
    const float* We1 = (const float*)d_in[8];
    const float* att1= (const float*)d_in[9];
    const float* b1  = (const float*)d_in[10];
    const float* g1  = (const float*)d_in[11];
    const float* be1 = (const float*)d_in[12];
    const float* m1  = (const float*)d_in[13];
    const float* v1  = (const float*)d_in[14];
    const float* Wl2 = (const float*)d_in[15];
    const float* bl2 = (const float*)d_in[16];
    const float* Wr2 = (const float*)d_in[17];
    const float* br2 = (const float*)d_in[18];
    const float* We2 = (const float*)d_in[19];
    const float* att2= (const float*)d_in[20];
    const float* b2  = (const float*)d_in[21];
    const float* g2  = (const float*)d_in[22];
    const float* be2 = (const float*)d_in[23];
    const float* m2  = (const float*)d_in[24];
    const float* v2  = (const float*)d_in[25];
    const float* Wf1 = (const float*)d_in[26];
    const float* bf1 = (const float*)d_in[27];
    const float* Wf2 = (const float*)d_in[28];
    const float* bf2 = (const float*)d_in[29];
    float* out = (float*)d_out;

    // ---- workspace layout (~210.3 MB; round-4 FULL proved >= 212.8 MB fits) ----
    const size_t PB = (size_t)NN * 256 * 4;       // 51.2 MB f32 panel
    const size_t WB = (size_t)262144 * 2;         // 0.5 MB bf16 weight copy
    char* ws = (char*)d_ws;
    size_t off = 0;
    float* bufA = (float*)(ws + off); off += PB;  // xl_h
    float* bufB = (float*)(ws + off); off += PB;  // xr_h -> h1_h (in-place via node_fused)
    float* xl2  = (float*)(ws + off); off += PB;
    float* xr2  = (float*)(ws + off); off += PB;  // -> h2 (in-place)
    unsigned short* Wl1h = (unsigned short*)(ws + off); off += WB;
    unsigned short* Wl1l = (unsigned short*)(ws + off); off += WB;
    unsigned short* Wr1h = (unsigned short*)(ws + off); off += WB;
    unsigned short* Wr1l = (unsigned short*)(ws + off); off += WB;
    unsigned short* Wl2h = (unsigned short*)(ws + off); off += WB;
    unsigned short* Wl2l = (unsigned short*)(ws + off); off += WB;
    unsigned short* Wr2h = (unsigned short*)(ws + off); off += WB;
    unsigned short* Wr2l = (unsigned short*)(ws + off); off += WB;
    int* cnt    = (int*)(ws + off); off += (size_t)NN * 4;
    int* csroff = (int*)(ws + off); off += ((size_t)(NN + 1) * 4 + 15) & ~15ull;
    int* cursor = (int*)(ws + off); off += (size_t)NN * 4;
    int* eidl   = (int*)(ws + off); off += (size_t)NE * 4;
    if (ws_size < off) {
        fill_val<<<(out_size + 255) / 256, 256, 0, stream>>>(out, out_size, 1e30f);
        return;
    }

    // ---- CSR build (once; reused by all 5 node passes) ----
    hipMemsetAsync(cnt, 0, (size_t)NN * 4, stream);
    csr_count<<<(NE + 255) / 256, 256, 0, stream>>>(ei, cnt);
    csr_offsets<<<1, 1024, 0, stream>>>(cnt, csroff, cursor);
    csr_fill<<<(NE + 255) / 256, 256, 0, stream>>>(ei, cursor, eidl);

    // ---- weight prep ----
    wsplit<<<1024, 256, 0, stream>>>(Wl1, Wl1h, Wl1l, 256, 1024);
    wsplit<<<1024, 256, 0, stream>>>(Wr1, Wr1h, Wr1l, 256, 1024);
    wsplit<<<1024, 256, 0, stream>>>(Wl2, Wl2h, Wl2l, 1024, 256);
    wsplit<<<1024, 256, 0, stream>>>(Wr2, Wr2h, Wr2l, 1024, 256);

    const dim3 gg((NN + 127) / 128, 2);
    const int nodeBlocks = NN / 16;   // 3125 exact

    // ================= layer 1, per head =================
    for (int h = 0; h < NH; ++h) {
        gemm_split<<<gg, 256, 0, stream>>>(
            x, Wl1h + (size_t)h * 65536, Wl1l + (size_t)h * 65536,
            bl1 + h * 256, bufA, NN, 256, 256, 256, 0);
        gemm_split<<<gg, 256, 0, stream>>>(
            x, Wr1h + (size_t)h * 65536, Wr1l + (size_t)h * 65536,
            br1 + h * 256, bufB, NN, 256, 256, 256, 0);
        node_fused<1><<<nodeBlocks, 1024, 0, stream>>>(
            bufA, bufB, csroff, eidl, ei, ea, We1 + h * 256, 1024, att1 + h * 256,
            b1 + h * 256, g1 + h * 256, be1 + h * 256, m1 + h * 256, v1 + h * 256,
            bufB);   // h1_h written over xr panel (safe: own-row read-before-write)
        // layer-2 partial-K accumulation (ldbt = 1024, K-chunk offset h*256)
        gemm_split<<<gg, 256, 0, stream>>>(
            bufB, Wl2h + h * 256, Wl2l + h * 256, bl2, xl2, NN, 256, 256, 1024,
            h > 0 ? 1 : 0);
        gemm_split<<<gg, 256, 0, stream>>>(
            bufB, Wr2h + h * 256, Wr2l + h * 256, br2, xr2, NN, 256, 256, 1024,
            h > 0 ? 1 : 0);
    }

    // ================= layer 2 (4 heads at once) =================
    node_fused<4><<<nodeBlocks, 1024, 0, stream>>>(
        xl2, xr2, csroff, eidl, ei, ea, We2, 256, att2,
        b2, g2, be2, m2, v2, xr2);   // h2 over xr2

    // ================= head MLP =================
    head_mlp<<<NG, 64, 0, stream>>>(xr2, nnd, Wf1, bf1, Wf2, bf2, out);
}

// Round 6
// 1636.447 us; speedup vs baseline: 3.1128x; 1.1915x over previous
//
#include <hip/hip_runtime.h>
#include <math.h>

#define NN 50000
#define NE 200000
#define NH 4
#define NG 100
#define EPSBN 1e-5f
#define SLOPE 0.2f

typedef __attribute__((ext_vector_type(8))) short bf16x8;
typedef __attribute__((ext_vector_type(4))) float f32x4;

__device__ __forceinline__ unsigned short f2bf(float f) {
    unsigned u = __float_as_uint(f);
    unsigned r = (u + 0x7fffu + ((u >> 16) & 1u)) >> 16;   // RNE
    return (unsigned short)r;
}
__device__ __forceinline__ float bf2f(unsigned short s) {
    return __uint_as_float(((unsigned)s) << 16);
}

__global__ void fill_val(float* p, int n, float v) {
    int i = blockIdx.x * 256 + threadIdx.x;
    if (i < n) p[i] = v;
}

// ---------- weight prep: fused [Wl|Wr] transposed split panels ----------
// L1: B1[h][r][k] = (r<256 ? Wl1 : Wr1)[k][h*256 + (r&255)], W* are [256,1024]
__global__ void wprep1(const float* __restrict__ Wl, const float* __restrict__ Wr,
                       unsigned short* __restrict__ Bh, unsigned short* __restrict__ Bl) {
    int idx = blockIdx.x * 256 + threadIdx.x;    // 4*512*256 total
    int k = idx & 255, r = (idx >> 8) & 511, h = idx >> 17;
    const float* W = (r < 256) ? Wl : Wr;
    float w = W[(size_t)k * 1024 + h * 256 + (r & 255)];
    unsigned short hi = f2bf(w);
    Bh[idx] = hi;
    Bl[idx] = f2bf(w - bf2f(hi));
}
// L2: B2[h][r][k] = (r<256 ? Wl2 : Wr2)[h*256+k][r&255], W* are [1024,256]
__global__ void wprep2(const float* __restrict__ Wl, const float* __restrict__ Wr,
                       unsigned short* __restrict__ Bh, unsigned short* __restrict__ Bl) {
    int idx = blockIdx.x * 256 + threadIdx.x;
    int k = idx & 255, r = (idx >> 8) & 511, h = idx >> 17;
    const float* W = (r < 256) ? Wl : Wr;
    float w = W[(size_t)(h * 256 + k) * 256 + (r & 255)];
    unsigned short hi = f2bf(w);
    Bh[idx] = hi;
    Bl[idx] = f2bf(w - bf2f(hi));
}

// ---------- fused split-bf16 MFMA GEMM: C[M,512] = A[M,256] @ Bt[512,256]^T ----------
// AF32: A f32 (split on the fly). !AF32: A pre-split bf16 (hi at Ah_g, lo at +alo).
// 128x128 tile, 256 thr = 4 waves (2x2), 4x4 frags of mfma_f32_16x16x32_bf16,
// 3 passes (AhBh + AlBh + AhBl). LDS XOR-swizzled. K=256, N=512, ldc=512.
template<bool AF32>
__launch_bounds__(256, 2)
__global__ void gemm_fused(const float* __restrict__ Af,
                           const unsigned short* __restrict__ Ah_g, int lda, int alo,
                           const unsigned short* __restrict__ Bh,
                           const unsigned short* __restrict__ Bl,
                           const float* __restrict__ bL, const float* __restrict__ bR,
                           float* __restrict__ C, int M, int accum) {
    __shared__ unsigned short Ahs[128 * 64];
    __shared__ unsigned short Als[128 * 64];
    __shared__ unsigned short Bhs[128 * 64];
    __shared__ unsigned short Bls[128 * 64];
    char* AhB = (char*)Ahs; char* AlB = (char*)Als;
    char* BhB = (char*)Bhs; char* BlB = (char*)Bls;
    const int tid = threadIdx.x;
    const int m0 = blockIdx.x * 128, n0 = blockIdx.y * 128;
    const int lane = tid & 63, wid = tid >> 6;
    const int wr = wid >> 1, wc = wid & 1;
    const int srow = tid >> 1, shalf = tid & 1;
    const int sbyte = shalf * 64;
    const int swz = (srow & 7) << 4;
    const bool ok = (m0 + srow) < M;

    f32x4 acc[4][4];
#pragma unroll
    for (int m = 0; m < 4; ++m)
#pragma unroll
        for (int n = 0; n < 4; ++n) acc[m][n] = (f32x4){0.f, 0.f, 0.f, 0.f};

    for (int k0 = 0; k0 < 256; k0 += 64) {
        if (AF32) {
            const float* Ap = Af + (size_t)(m0 + srow) * lda + k0 + shalf * 32;
#pragma unroll
            for (int i = 0; i < 4; ++i) {
                float vv[8];
                if (ok) {
                    *(float4*)&vv[0] = *(const float4*)(Ap + i * 8);
                    *(float4*)&vv[4] = *(const float4*)(Ap + i * 8 + 4);
                } else {
#pragma unroll
                    for (int j = 0; j < 8; ++j) vv[j] = 0.f;
                }
                uint4 uh, ul;
                unsigned* uhp = &uh.x; unsigned* ulp = &ul.x;
#pragma unroll
                for (int j = 0; j < 4; ++j) {
                    float a0 = vv[2 * j], a1 = vv[2 * j + 1];
                    unsigned short h0 = f2bf(a0), h1 = f2bf(a1);
                    unsigned short l0 = f2bf(a0 - bf2f(h0)), l1 = f2bf(a1 - bf2f(h1));
                    uhp[j] = (unsigned)h0 | ((unsigned)h1 << 16);
                    ulp[j] = (unsigned)l0 | ((unsigned)l1 << 16);
                }
                *(uint4*)(AhB + srow * 128 + ((sbyte + i * 16) ^ swz)) = uh;
                *(uint4*)(AlB + srow * 128 + ((sbyte + i * 16) ^ swz)) = ul;
            }
        } else {
            const unsigned short* Ap = Ah_g + (size_t)(m0 + srow) * lda + k0 + shalf * 32;
#pragma unroll
            for (int i = 0; i < 4; ++i) {
                uint4 uh = ok ? *(const uint4*)(Ap + i * 8) : make_uint4(0, 0, 0, 0);
                uint4 ul = ok ? *(const uint4*)(Ap + alo + i * 8) : make_uint4(0, 0, 0, 0);
                *(uint4*)(AhB + srow * 128 + ((sbyte + i * 16) ^ swz)) = uh;
                *(uint4*)(AlB + srow * 128 + ((sbyte + i * 16) ^ swz)) = ul;
            }
        }
        {
            const unsigned short* Bp = Bh + (size_t)(n0 + srow) * 256 + k0 + shalf * 32;
            const unsigned short* Bq = Bl + (size_t)(n0 + srow) * 256 + k0 + shalf * 32;
#pragma unroll
            for (int i = 0; i < 4; ++i) {
                *(uint4*)(BhB + srow * 128 + ((sbyte + i * 16) ^ swz)) =
                    *(const uint4*)(Bp + i * 8);
                *(uint4*)(BlB + srow * 128 + ((sbyte + i * 16) ^ swz)) =
                    *(const uint4*)(Bq + i * 8);
            }
        }
        __syncthreads();
#pragma unroll
        for (int kk = 0; kk < 2; ++kk) {
            const int kb = kk * 64 + (lane >> 4) * 16;
            bf16x8 ah[4], al[4], bh[4], bl[4];
#pragma unroll
            for (int m = 0; m < 4; ++m) {
                int row = wr * 64 + m * 16 + (lane & 15);
                int off = row * 128 + (kb ^ ((row & 7) << 4));
                ah[m] = *(const bf16x8*)(AhB + off);
                al[m] = *(const bf16x8*)(AlB + off);
            }
#pragma unroll
            for (int n = 0; n < 4; ++n) {
                int row = wc * 64 + n * 16 + (lane & 15);
                int off = row * 128 + (kb ^ ((row & 7) << 4));
                bh[n] = *(const bf16x8*)(BhB + off);
                bl[n] = *(const bf16x8*)(BlB + off);
            }
#pragma unroll
            for (int m = 0; m < 4; ++m)
#pragma unroll
                for (int n = 0; n < 4; ++n) {
                    acc[m][n] = __builtin_amdgcn_mfma_f32_16x16x32_bf16(
                        ah[m], bh[n], acc[m][n], 0, 0, 0);
                    acc[m][n] = __builtin_amdgcn_mfma_f32_16x16x32_bf16(
                        al[m], bh[n], acc[m][n], 0, 0, 0);
                    acc[m][n] = __builtin_amdgcn_mfma_f32_16x16x32_bf16(
                        ah[m], bl[n], acc[m][n], 0, 0, 0);
                }
        }
        __syncthreads();
    }
#pragma unroll
    for (int n = 0; n < 4; ++n) {
        int gcol = n0 + wc * 64 + n * 16 + (lane & 15);
        float bv = accum ? 0.f : (gcol < 256 ? bL[gcol] : bR[gcol - 256]);
#pragma unroll
        for (int m = 0; m < 4; ++m) {
#pragma unroll
            for (int r = 0; r < 4; ++r) {
                int grow = m0 + wr * 64 + m * 16 + (lane >> 4) * 4 + r;
                if (grow < M) {
                    size_t o = (size_t)grow * 512 + gcol;
                    C[o] = accum ? (C[o] + acc[m][n][r]) : (acc[m][n][r] + bv);
                }
            }
        }
    }
}

// ---------- CSR build over dst (verified round 5) ----------
__global__ void csr_count(const int* __restrict__ ei, int* __restrict__ cnt) {
    int e = blockIdx.x * 256 + threadIdx.x;
    if (e < NE) atomicAdd(&cnt[ei[NE + e]], 1);
}
__launch_bounds__(1024)
__global__ void csr_offsets(const int* __restrict__ cnt, int* __restrict__ off,
                            int* __restrict__ cursor) {
    __shared__ int s[1024];
    const int t = threadIdx.x;
    const int PER = 49;
    const int base = t * PER;
    int sum = 0;
    for (int i = 0; i < PER; ++i) {
        int idx = base + i;
        if (idx < NN) sum += cnt[idx];
    }
    s[t] = sum;
    __syncthreads();
    for (int d = 1; d < 1024; d <<= 1) {
        int v = (t >= d) ? s[t - d] : 0;
        __syncthreads();
        s[t] += v;
        __syncthreads();
    }
    int run = s[t] - sum;
    for (int i = 0; i < PER; ++i) {
        int idx = base + i;
        if (idx < NN) {
            off[idx] = run;
            cursor[idx] = run;
            run += cnt[idx];
            if (idx == NN - 1) off[NN] = run;
        }
    }
}
__global__ void csr_fill(const int* __restrict__ ei, int* __restrict__ cursor,
                         int* __restrict__ eidl) {
    int e = blockIdx.x * 256 + threadIdx.x;
    if (e < NE) {
        int d = ei[NE + e];
        int p = atomicAdd(&cursor[d], 1);
        eidl[p] = e;
    }
}

// ---------- per-edge logit partial (4 channels/lane, register We) ----------
__device__ __forceinline__ float edge_part(const float4& l, const float4& r,
                                           const float* ev, const float (*rW)[4],
                                           const float4& attv) {
    const float* lp = &l.x; const float* rp = &r.x; const float* ap = &attv.x;
    float part = 0.f;
#pragma unroll
    for (int j = 0; j < 4; ++j) {
        float ecf = 0.f;
#pragma unroll
        for (int d = 0; d < 12; ++d) ecf = fmaf(ev[d], rW[d][j], ecf);
        float mv = lp[j] + rp[j] + ecf;
        mv = mv > 0.f ? mv : SLOPE * mv;
        part = fmaf(mv, ap[j], part);
    }
    return part;
}

// ---------- fused node pass: softmax-aggregate + bias+relu+bn ----------
// 256 thr = 4 waves = 4 nodes/block; one wave per node, 4 channels/lane.
// xlr rows: xl = cols 0-255, xr = cols 256-511 (stride 512).
// OUTSPLIT: write h1 as split bf16 (hi|lo) over own row's xr half (dead after read).
// else: write f32 over own row's xr half.
template<int NHEADS, bool OUTSPLIT>
__launch_bounds__(256)
__global__ void node_fused(float* __restrict__ xlr,
                           const int* __restrict__ off, const int* __restrict__ eidl,
                           const int* __restrict__ ei, const float* __restrict__ ea,
                           const float* __restrict__ We, int ldwe,
                           const float* __restrict__ att,
                           const float* __restrict__ bias, const float* __restrict__ gam,
                           const float* __restrict__ bet, const float* __restrict__ mu,
                           const float* __restrict__ var) {
    const int n = blockIdx.x * 4 + (threadIdx.x >> 6);
    const int lane = threadIdx.x & 63;
    const int cf = lane * 4;
    float rW[12][4];
#pragma unroll
    for (int d = 0; d < 12; ++d) {
        float4 w = *(const float4*)&We[(size_t)d * ldwe + cf];
        rW[d][0] = w.x; rW[d][1] = w.y; rW[d][2] = w.z; rW[d][3] = w.w;
    }
    const float4 attv = *(const float4*)&att[cf];
    float* xrow = xlr + (size_t)n * 512;
    const float4 xr4 = *(const float4*)(xrow + 256 + cf);
    float acc[4] = {0.f, 0.f, 0.f, 0.f};
    float den = 0.f;
    const int beg = off[n], end = off[n + 1];
    constexpr int RED = 64 / NHEADS;   // 64 (1 head) | 16 (4 heads)
    int k = beg;
    for (; k + 2 <= end; k += 2) {     // unroll-2 for ILP
        int e0 = eidl[k], e1 = eidl[k + 1];
        int s0 = ei[e0], s1 = ei[e1];
        float ev0[12], ev1[12];
        const float2* p0 = (const float2*)(ea + (size_t)e0 * 12);
        const float2* p1 = (const float2*)(ea + (size_t)e1 * 12);
#pragma unroll
        for (int d = 0; d < 6; ++d) {
            float2 a = p0[d], b = p1[d];
            ev0[2 * d] = a.x; ev0[2 * d + 1] = a.y;
            ev1[2 * d] = b.x; ev1[2 * d + 1] = b.y;
        }
        float4 l0 = *(const float4*)(xlr + (size_t)s0 * 512 + cf);
        float4 l1 = *(const float4*)(xlr + (size_t)s1 * 512 + cf);
        float pa = edge_part(l0, xr4, ev0, rW, attv);
        float pb = edge_part(l1, xr4, ev1, rW, attv);
#pragma unroll
        for (int o = RED / 2; o > 0; o >>= 1) {
            pa += __shfl_xor(pa, o);
            pb += __shfl_xor(pb, o);
        }
        float ex0 = __expf(pa), ex1 = __expf(pb);
        den += ex0 + ex1;
        const float* lp0 = &l0.x; const float* lp1 = &l1.x;
#pragma unroll
        for (int j = 0; j < 4; ++j)
            acc[j] = fmaf(ex0, lp0[j], fmaf(ex1, lp1[j], acc[j]));
    }
    if (k < end) {
        int e0 = eidl[k];
        int s0 = ei[e0];
        float ev0[12];
        const float2* p0 = (const float2*)(ea + (size_t)e0 * 12);
#pragma unroll
        for (int d = 0; d < 6; ++d) {
            float2 a = p0[d];
            ev0[2 * d] = a.x; ev0[2 * d + 1] = a.y;
        }
        float4 l0 = *(const float4*)(xlr + (size_t)s0 * 512 + cf);
        float pa = edge_part(l0, xr4, ev0, rW, attv);
#pragma unroll
        for (int o = RED / 2; o > 0; o >>= 1) pa += __shfl_xor(pa, o);
        float ex0 = __expf(pa);
        den += ex0;
        const float* lp0 = &l0.x;
#pragma unroll
        for (int j = 0; j < 4; ++j) acc[j] = fmaf(ex0, lp0[j], acc[j]);
    }
    const float inv = 1.f / (den + 1e-16f);
    float o[4];
#pragma unroll
    for (int j = 0; j < 4; ++j) {
        int c = cf + j;
        float t = fmaxf(acc[j] * inv + bias[c], 0.f);
        o[j] = (t - mu[c]) * rsqrtf(var[c] + EPSBN) * gam[c] + bet[c];
    }
    if (OUTSPLIT) {
        unsigned short* oh = (unsigned short*)(xrow + 256);   // hi: shorts [0,256)
        ushort4 hv, lv;
        unsigned short h0 = f2bf(o[0]), h1 = f2bf(o[1]), h2 = f2bf(o[2]), h3 = f2bf(o[3]);
        hv.x = h0; hv.y = h1; hv.z = h2; hv.w = h3;
        lv.x = f2bf(o[0] - bf2f(h0)); lv.y = f2bf(o[1] - bf2f(h1));
        lv.z = f2bf(o[2] - bf2f(h2)); lv.w = f2bf(o[3] - bf2f(h3));
        *(ushort4*)(oh + cf) = hv;
        *(ushort4*)(oh + 256 + cf) = lv;                      // lo: shorts [256,512)
    } else {
        *(float4*)(xrow + 256 + cf) = make_float4(o[0], o[1], o[2], o[3]);
    }
}

// ---------- head MLP (h2 at xlr2 rows, cols 256-511, stride 512) ----------
__launch_bounds__(64)
__global__ void head_mlp(const float* __restrict__ h2, const int* __restrict__ n_nodes,
                         const float* __restrict__ Wf1, const float* __restrict__ bf1,
                         const float* __restrict__ Wf2, const float* __restrict__ bf2,
                         float* __restrict__ out) {
    const int g = blockIdx.x;
    const int t = threadIdx.x;
    int acc = 0;
    for (int i = t; i <= g; i += 64) acc += n_nodes[i];
#pragma unroll
    for (int off = 32; off > 0; off >>= 1) acc += __shfl_xor(acc, off);
    const int node = acc - 1;
    __shared__ float row[256];
    for (int i = t; i < 256; i += 64) row[i] = h2[(size_t)node * 512 + 256 + i];
    __syncthreads();
    float hid = bf1[t];
    for (int k = 0; k < 256; ++k) hid = fmaf(row[k], Wf1[k * 64 + t], hid);
    hid = fmaxf(hid, 0.f);
    float p = hid * Wf2[t];
#pragma unroll
    for (int off = 32; off > 0; off >>= 1) p += __shfl_xor(p, off);
    if (t == 0) out[g] = p + bf2[0];
}

extern "C" void kernel_launch(void* const* d_in, const int* in_sizes, int n_in,
                              void* d_out, int out_size, void* d_ws, size_t ws_size,
                              hipStream_t stream) {
    const float* x   = (const float*)d_in[0];
    const int*   ei  = (const int*)d_in[1];
    const float* ea  = (const float*)d_in[2];
    const int*   nnd = (const int*)d_in[3];
    const float* Wl1 = (const float*)d_in[4];
    const float* bl1 = (const float*)d_in[5];
    const float* Wr1 = (const float*)d_in[6];
    const float* br1 = (const float*)d_in[7];
    const float* We1 = (const float*)d_in[8];
    const float* att1= (const float*)d_in[9];
    const float* b1  = (const float*)d_in[10];
    const float* g1  = (const float*)d_in[11];
    const float* be1 = (const float*)d_in[12];
    const float* m1  = (const float*)d_in[13];
    const float* v1  = (const float*)d_in[14];
    const float* Wl2 = (const float*)d_in[15];
    const float* bl2 = (const float*)d_in[16];
    const float* Wr2 = (const float*)d_in[17];
    const float* br2 = (const float*)d_in[18];
    const float* We2 = (const float*)d_in[19];
    const float* att2= (const float*)d_in[20];
    const float* b2  = (const float*)d_in[21];
    const float* g2  = (const float*)d_in[22];
    const float* be2 = (const float*)d_in[23];
    const float* m2  = (const float*)d_in[24];
    const float* v2  = (const float*)d_in[25];
    const float* Wf1 = (const float*)d_in[26];
    const float* bf1 = (const float*)d_in[27];
    const float* Wf2 = (const float*)d_in[28];
    const float* bf2 = (const float*)d_in[29];
    float* out = (float*)d_out;

    // ---- workspace (~210.3 MB; proven >= 213.0 MB available) ----
    const size_t XB = (size_t)NN * 512 * 4;       // 102.4 MB fused panel
    const size_t WB = (size_t)4 * 512 * 256 * 2;  // 1 MB per split half (all heads)
    char* ws = (char*)d_ws;
    size_t off = 0;
    float* xlr  = (float*)(ws + off); off += XB;
    float* xlr2 = (float*)(ws + off); off += XB;
    unsigned short* B1h = (unsigned short*)(ws + off); off += WB;
    unsigned short* B1l = (unsigned short*)(ws + off); off += WB;
    unsigned short* B2h = (unsigned short*)(ws + off); off += WB;
    unsigned short* B2l = (unsigned short*)(ws + off); off += WB;
    int* cnt    = (int*)(ws + off); off += (size_t)NN * 4;
    int* csroff = (int*)(ws + off); off += ((size_t)(NN + 1) * 4 + 15) & ~15ull;
    int* cursor = (int*)(ws + off); off += (size_t)NN * 4;
    int* eidl   = (int*)(ws + off); off += (size_t)NE * 4;
    if (ws_size < off) {
        fill_val<<<(out_size + 255) / 256, 256, 0, stream>>>(out, out_size, 1e30f);
        return;
    }

    // ---- CSR build (once) ----
    hipMemsetAsync(cnt, 0, (size_t)NN * 4, stream);
    csr_count<<<(NE + 255) / 256, 256, 0, stream>>>(ei, cnt);
    csr_offsets<<<1, 1024, 0, stream>>>(cnt, csroff, cursor);
    csr_fill<<<(NE + 255) / 256, 256, 0, stream>>>(ei, cursor, eidl);

    // ---- weight prep ----
    wprep1<<<2048, 256, 0, stream>>>(Wl1, Wr1, B1h, B1l);
    wprep2<<<2048, 256, 0, stream>>>(Wl2, Wr2, B2h, B2l);

    const dim3 gg((NN + 127) / 128, 4);   // 391 x 4 (N=512)
    const int nodeBlocks = NN / 4;        // 12500 exact

    for (int h = 0; h < NH; ++h) {
        // xlr = [x@Wl1_h + bl | x@Wr1_h + br]
        gemm_fused<true><<<gg, 256, 0, stream>>>(
            x, nullptr, 256, 0, B1h + (size_t)h * 131072, B1l + (size_t)h * 131072,
            bl1 + h * 256, br1 + h * 256, xlr, NN, 0);
        // softmax-aggregate + bn -> h1_h split-bf16 over xr half
        node_fused<1, true><<<nodeBlocks, 256, 0, stream>>>(
            xlr, csroff, eidl, ei, ea, We1 + h * 256, 1024, att1 + h * 256,
            b1 + h * 256, g1 + h * 256, be1 + h * 256, m1 + h * 256, v1 + h * 256);
        // xlr2 (+)= [h1_h@Wl2_chunk | h1_h@Wr2_chunk]  (A = pre-split bf16)
        gemm_fused<false><<<gg, 256, 0, stream>>>(
            nullptr, (const unsigned short*)xlr + 512, 1024, 256,
            B2h + (size_t)h * 131072, B2l + (size_t)h * 131072,
            bl2, br2, xlr2, NN, h > 0 ? 1 : 0);
    }

    // layer-2 attention (4 heads), output f32 over xr half of xlr2
    node_fused<4, false><<<nodeBlocks, 256, 0, stream>>>(
        xlr2, csroff, eidl, ei, ea, We2, 256, att2, b2, g2, be2, m2, v2);

    head_mlp<<<NG, 64, 0, stream>>>(xlr2, nnd, Wf1, bf1, Wf2, bf2, out);
}